// Round 11
// baseline (407.360 us; speedup 1.0000x reference)
//
#include <hip/hip_runtime.h>
#include <stdint.h>

#define DEVI __device__ __forceinline__

typedef __attribute__((ext_vector_type(4))) float     f4v;
typedef __attribute__((ext_vector_type(8))) _Float16  h8;
typedef __attribute__((ext_vector_type(4))) _Float16  h4;
typedef unsigned int  u32;

static constexpr int   TQ = 1024, TKN = 512;
static constexpr float KEY_RATE = 1.385f;
static constexpr float QRY_RATE = 1.0f;
static constexpr float SCALE    = 0.04419417382415922f;   // sqrt(1/512)
static constexpr float INVC     = 0.05190512648261504f;   // log2(10000)/256

// ---------------- workspace layout (bytes) ----------------
static constexpr size_t OFF_MM   = 0;                                  // fp16 [512][512]  Mm = Wq Wk^T
static constexpr size_t OFF_NT   = OFF_MM  + (size_t)512*512*2;        // fp16 [512][512]  Nt = (Wv Wo)^T
static constexpr size_t OFF_WOT  = OFF_NT  + (size_t)512*512*2;        // f32  [512][512]  Wo^T
static constexpr size_t OFF_PEQ  = OFF_WOT + (size_t)512*512*4;        // f32  [1024][512]
static constexpr size_t OFF_W    = OFF_PEQ + (size_t)1024*512*4;       // f32  [512]
static constexpr size_t OFF_C    = OFF_W   + 2048;                     // f32  [512]
static constexpr size_t OFF_BQBK = OFF_C   + 2048;                     // f32  [1]
static constexpr size_t OFF_T    = OFF_BQBK + 256;                     // f32  [64][512] tvec_eff
static constexpr size_t OFF_KP   = OFF_T   + (size_t)64*512*4;         // fp16 [64][512][512] k' = keys+pe
static constexpr size_t OFF_MKT  = OFF_KP  + (size_t)64*512*512*2;     // fp16 [64][512][512] MKt[t][c]
static constexpr size_t OFF_PT   = OFF_MKT + (size_t)64*512*512*2;     // fp16 [64][512][512] Pt[e][t]
static constexpr size_t WS_NEED  = OFF_PT  + (size_t)64*512*512*2;     // ~105 MB

#define WAITV(N) asm volatile("s_waitcnt vmcnt(" #N ")" ::: "memory")
#define WAITL()  asm volatile("s_waitcnt lgkmcnt(0)" ::: "memory")
#define SCHEDB() __builtin_amdgcn_sched_barrier(0)
#define BARRAW() __builtin_amdgcn_s_barrier()

// ---------------- core helpers (BM=128, BN=512, BK=32 template) ----------------
DEVI f4v mfma16(h8 a, h8 b, f4v c) {
  return __builtin_amdgcn_mfma_f32_16x16x32_f16(a, b, c, 0, 0, 0);
}

DEVI void gld16(void* lds, const void* g) {
  __builtin_amdgcn_global_load_lds(
      (const __attribute__((address_space(1))) unsigned int*)g,
      (__attribute__((address_space(3))) unsigned int*)lds, 16, 0, 0);
}

// B panel: 512 rows x 32 cols fp16 (row stride 512): slot s holds chunk s^((r>>1)&3). 4 gld16/thread.
DEVI void stage_B(char* Bbuf, const _Float16* B, int k0, int tid) {
#pragma unroll
  for (int it = 0; it < 4; ++it) {
    const int c = (it << 9) + tid;              // 0..2047 16B chunks
    const int r = c >> 2, s = c & 3;
    const int sg = s ^ ((r >> 1) & 3);
    gld16(Bbuf + ((size_t)c << 4), B + (size_t)r * 512 + k0 + (sg << 3));
  }
}

// A tile fp16: 128 rows x 32 cols (row stride 512). 1 gld16/thread.
DEVI void stage_A16(char* Abuf, const _Float16* A, int k0, int tid) {
  const int r = tid >> 2, s = tid & 3;
  const int sg = s ^ ((r >> 1) & 3);
  gld16(Abuf + ((size_t)tid << 4), A + (size_t)r * 512 + k0 + (sg << 3));
}

// A tile fp32 source: issue loads (early) ...
DEVI void loads_A32(f4v& x0, f4v& x1, const float* A, const float* add, int k0, int tid) {
  const int r = tid >> 2, c8 = (tid & 3) << 3;
  const float* p = A + (size_t)r * 512 + k0 + c8;
  x0 = *(const f4v*)p; x1 = *(const f4v*)(p + 4);
  if (add) {
    const float* q = add + (size_t)r * 512 + k0 + c8;
    x0 += *(const f4v*)q; x1 += *(const f4v*)(q + 4);
  }
}
// ... convert+write (late)
DEVI void write_A32(char* Abuf, f4v x0, f4v x1, int tid) {
  const int r = tid >> 2;
  const int slot = (tid & 3) ^ ((r >> 1) & 3);
  h8 o;
#pragma unroll
  for (int i = 0; i < 4; ++i) { o[i] = (_Float16)x0[i]; o[4 + i] = (_Float16)x1[i]; }
  *(h8*)(Abuf + (r << 6) + (slot << 4)) = o;
}

DEVI void read_fragsA(const char* Ab, int wr, int lane, h8 (&a)[4]) {
  const int l15 = lane & 15, hi = lane >> 4;
#pragma unroll
  for (int mi = 0; mi < 4; ++mi) {
    const int r = wr * 64 + mi * 16 + l15;
    a[mi] = *(const h8*)(Ab + (r << 6) + ((hi ^ ((r >> 1) & 3)) << 4));
  }
}
DEVI void read_fragsB(const char* Bb, int wc, int lane, h8 (&b)[8]) {
  const int l15 = lane & 15, hi = lane >> 4;
#pragma unroll
  for (int nj = 0; nj < 8; ++nj) {
    const int g = wc * 128 + nj * 16 + l15;
    b[nj] = *(const h8*)(Bb + (g << 6) + ((hi ^ ((g >> 1) & 3)) << 4));
  }
}

#define MFMA_ALL(a, bf, acc)                                   \
  _Pragma("unroll") for (int mi = 0; mi < 4; ++mi)             \
  _Pragma("unroll") for (int nj = 0; nj < 8; ++nj)             \
      acc[mi][nj] = mfma16(a[mi], bf[nj], acc[mi][nj]);

// ---- REG-A pipeline: A f32 (+opt add) reg-staged 2-deep, B gld16 3-deep, counted vmcnt ----
// LDS map: A0@0, A1@8K, B0@16K, B1@48K, B2@80K  (112KB)
#define REG_PIPELINE(As, Ad, Bs, acc)                                              \
  {                                                                                \
    char* const Abf[2] = {lds, lds + 8192};                                        \
    char* const Bbf[3] = {lds + 16384, lds + 49152, lds + 81920};                  \
    f4v xa0, xa1, xb0, xb1;                                                        \
    loads_A32(xa0, xa1, As, Ad, 0, tid);                                           \
    loads_A32(xb0, xb1, As, Ad, 32, tid);                                          \
    SCHEDB();                                                                      \
    stage_B(Bbf[0], Bs, 0, tid);                                                   \
    stage_B(Bbf[1], Bs, 32, tid);                                                  \
    WAITV(4);                                                                      \
    write_A32(Abf[0], xa0, xa1, tid);                                              \
    WAITL(); SCHEDB(); BARRAW(); SCHEDB();                                         \
    _Pragma("unroll")                                                              \
    for (int k = 0; k < 16; ++k) {                                                 \
      if (k < 14) {                                                                \
        if ((k & 1) == 0) { loads_A32(xa0, xa1, As, Ad, (k + 2) * 32, tid); }      \
        else              { loads_A32(xb0, xb1, As, Ad, (k + 2) * 32, tid); }      \
        SCHEDB();                                                                  \
        stage_B(Bbf[(k + 2) % 3], Bs, (k + 2) * 32, tid);                          \
      }                                                                            \
      h8 a[4], bf[8];                                                              \
      read_fragsA(Abf[k & 1], wr, lane, a);                                        \
      read_fragsB(Bbf[k % 3], wc, lane, bf);                                       \
      MFMA_ALL(a, bf, acc);                                                        \
      if (k < 15) {                                                                \
        if (k < 14) { WAITV(6); } else { WAITV(0); }                               \
        if ((k & 1) == 0) write_A32(Abf[1], xb0, xb1, tid);                        \
        else              write_A32(Abf[0], xa0, xa1, tid);                        \
        WAITL(); SCHEDB(); BARRAW(); SCHEDB();                                     \
      }                                                                            \
    }                                                                              \
  }

// ---- GLD-A pipeline loop: A fp16 gld16 3-deep, B gld16 3-deep ----
// LDS map: A0@0, A1@8K, A2@16K, B0@24K, B1@56K, B2@88K  (120KB)
#define GLD_PIPELINE(As, Bs, acc)                                                  \
  {                                                                                \
    char* const Abf[3] = {lds, lds + 8192, lds + 16384};                           \
    char* const Bbf[3] = {lds + 24576, lds + 57344, lds + 90112};                  \
    stage_A16(Abf[0], As, 0, tid);  stage_B(Bbf[0], Bs, 0, tid);                   \
    stage_A16(Abf[1], As, 32, tid); stage_B(Bbf[1], Bs, 32, tid);                  \
    WAITV(5); SCHEDB(); BARRAW(); SCHEDB();                                        \
    _Pragma("unroll")                                                              \
    for (int k = 0; k < 16; ++k) {                                                 \
      if (k < 14) {                                                                \
        stage_A16(Abf[(k + 2) % 3], As, (k + 2) * 32, tid);                        \
        stage_B(Bbf[(k + 2) % 3], Bs, (k + 2) * 32, tid);                          \
      }                                                                            \
      h8 a[4], bf[8];                                                              \
      read_fragsA(Abf[k % 3], wr, lane, a);                                        \
      read_fragsB(Bbf[k % 3], wc, lane, bf);                                       \
      MFMA_ALL(a, bf, acc);                                                        \
      if (k < 14) { WAITV(5); } else if (k == 14) { WAITV(0); }                    \
      if (k < 15) { WAITL(); SCHEDB(); BARRAW(); SCHEDB(); }                       \
    }                                                                              \
  }

// reg-stage f32 tiles for the tiny weight-product GEMM (single-buffered)
DEVI void stage_f32_A(char* Abuf, const float* A, int k0, int tid) {
#pragma unroll
  for (int it = 0; it < 2; ++it) {
    const int idx = (it << 9) + tid;
    const int r = idx >> 3, c4 = idx & 7;
    f4v x = *(const f4v*)(A + (size_t)r * 512 + k0 + (c4 << 2));
    h4 o;
#pragma unroll
    for (int i = 0; i < 4; ++i) o[i] = (_Float16)x[i];
    const int slot = (c4 >> 1) ^ ((r >> 1) & 3);
    *(h4*)(Abuf + (r << 6) + (slot << 4) + ((c4 & 1) << 3)) = o;
  }
}
DEVI void stage_f32_B(char* Bbuf, const float* B, int k0, int tid) {
#pragma unroll
  for (int it = 0; it < 8; ++it) {
    const int idx = (it << 9) + tid;
    const int r = idx >> 3, c4 = idx & 7;
    f4v x = *(const f4v*)(B + (size_t)r * 512 + k0 + (c4 << 2));
    h4 o;
#pragma unroll
    for (int i = 0; i < 4; ++i) o[i] = (_Float16)x[i];
    const int slot = (c4 >> 1) ^ ((r >> 1) & 3);
    *(h4*)(Bbuf + (r << 6) + (slot << 4) + ((c4 & 1) << 3)) = o;
  }
}

// ---------------- prepA: wvec/bqbk + PEQ + Wo^T  (256 threads) ----------------
__global__ __launch_bounds__(256) void k_prepA(
    const float* __restrict__ Wk, const float* __restrict__ bq,
    const float* __restrict__ bk,
    const float* __restrict__ Wo,
    const void* __restrict__ fpos_raw,
    float* __restrict__ wvec, float* __restrict__ bqbk,
    float* __restrict__ PEQ, float* __restrict__ WoT) {
  const int bid = blockIdx.x, tid = threadIdx.x;
  if (bid < 128) {                       // wvec: 4 rows/block, 1 per wave
    const int wid = tid >> 6, lane = tid & 63;
    const int row = bid * 4 + wid;
    const float* p = Wk + (size_t)row * 512 + lane * 8;
    const f4v a = *(const f4v*)p, c = *(const f4v*)(p + 4);
    const f4v b0 = *(const f4v*)(bq + lane * 8), b1 = *(const f4v*)(bq + lane * 8 + 4);
    float d = a[0]*b0[0]+a[1]*b0[1]+a[2]*b0[2]+a[3]*b0[3]
            + c[0]*b1[0]+c[1]*b1[1]+c[2]*b1[2]+c[3]*b1[3];
#pragma unroll
    for (int off = 32; off; off >>= 1) d += __shfl_xor(d, off);
    if (lane == 0) wvec[row] = d;
  } else if (bid == 128) {               // bqbk
    __shared__ float red[256];
    red[tid] = bq[tid] * bk[tid] + bq[tid + 256] * bk[tid + 256];
    __syncthreads();
    if (tid == 0) { float s = 0.f; for (int h = 0; h < 256; ++h) s += red[h]; bqbk[0] = s; }
  } else if (bid < 129 + 2048) {         // PEQ
    const u32* fp = (const u32*)fpos_raw;
    const bool is64 = (fp[1] == 0);
    const int t = (bid - 129) * 256 + tid;
    const int tq = t >> 9, d = t & 511;
    const int pos = (int)(is64 ? fp[2 * tq] : fp[tq]);
    float pe = 0.f;
    if (pos != 0) {
      const float invf = exp2f(-(float)(d >> 1) * INVC);
      const float ang  = ((float)pos * QRY_RATE) * invf;
      pe = (d & 1) ? cosf(ang) : sinf(ang);
    }
    PEQ[t] = pe;
  } else {                               // Wo^T 32x32 tiles
    __shared__ float t[32][33];
    const int local = bid - 2177;
    const int bx = local & 15, by = local >> 4;
    const int tx = tid & 31, ty = tid >> 5;
    const int x = bx * 32 + tx;
#pragma unroll
    for (int j = 0; j < 4; ++j)
      t[ty + 8 * j][tx] = Wo[(size_t)(by * 32 + ty + 8 * j) * 512 + x];
    __syncthreads();
    const int x2 = by * 32 + tx;
#pragma unroll
    for (int j = 0; j < 4; ++j)
      WoT[(size_t)(bx * 32 + ty + 8 * j) * 512 + x2] = t[tx][ty + 8 * j];
  }
}

// ---------------- prepB: weight-product GEMMs + key prep + cvec  (512 threads) ----------------
__global__ __launch_bounds__(512) void k_prepB(
    const float* __restrict__ Wq, const float* __restrict__ Wk,
    const float* __restrict__ WoT, const float* __restrict__ Wv,
    const float* __restrict__ keys, const void* __restrict__ tpos_raw,
    const void* __restrict__ mask_raw,
    const float* __restrict__ wvec, const float* __restrict__ bqbk,
    const float* __restrict__ bv, const float* __restrict__ bo,
    _Float16* __restrict__ Mm, _Float16* __restrict__ Nt,
    _Float16* __restrict__ kp, float* __restrict__ tvec,
    float* __restrict__ cvec) {
  __shared__ char lds[40960];
  const int bid = blockIdx.x, tid = threadIdx.x;
  const int lane = tid & 63, wid = tid >> 6;
  if (bid < 8) {                         // weight products
    char *Ab = lds, *Bb = lds + 8192;
    const int wr = wid >> 2, wc = wid & 3;
    const int x = bid & 3, y = bid >> 2;
    const float* A = (y == 0 ? Wq : WoT) + (size_t)x * 128 * 512;
    const float* B = (y == 0 ? Wk : Wv);
    _Float16* out = (y == 0 ? Mm : Nt) + (size_t)x * 128 * 512;
    f4v acc[4][8] = {};
    for (int ks = 0; ks < 16; ++ks) {
      stage_f32_A(Ab, A, ks * 32, tid);
      stage_f32_B(Bb, B, ks * 32, tid);
      __syncthreads();
      h8 a[4], bf[8];
      read_fragsA(Ab, wr, lane, a);
      read_fragsB(Bb, wc, lane, bf);
      MFMA_ALL(a, bf, acc);
      __syncthreads();
    }
    const int l15 = lane & 15, hi = lane >> 4;
#pragma unroll
    for (int mi = 0; mi < 4; ++mi)
#pragma unroll
      for (int nj = 0; nj < 8; ++nj) {
        const int col = wc * 128 + nj * 16 + l15;
#pragma unroll
        for (int j = 0; j < 4; ++j) {
          const int row = wr * 64 + mi * 16 + hi * 4 + j;
          out[(size_t)row * 512 + col] = (_Float16)acc[mi][nj][j];
        }
      }
  } else if (bid < 4104) {               // key prep: 8 rows/block
    const u32* tp = (const u32*)tpos_raw;
    const bool is64 = (tp[1] == 0);
    const int row = (bid - 8) * 8 + wid;
    const int pos = (int)(is64 ? tp[2 * row] : tp[row]);
    const int d0  = lane * 8;
    const float* src = keys + (size_t)row * 512 + d0;
    const f4v a = *(const f4v*)src, b = *(const f4v*)(src + 4);
    float x[8] = {a[0], a[1], a[2], a[3], b[0], b[1], b[2], b[3]};
    if (pos != 0) {
      const float pw = (float)pos * KEY_RATE;
#pragma unroll
      for (int u = 0; u < 4; ++u) {
        const float invf = exp2f(-(float)(lane * 4 + u) * INVC);
        const float ang  = pw * invf;
        x[2*u]   += sinf(ang);
        x[2*u+1] += cosf(ang);
      }
    }
    const f4v w0 = *(const f4v*)(wvec + d0), w1 = *(const f4v*)(wvec + d0 + 4);
    float dot = 0.f;
#pragma unroll
    for (int i = 0; i < 4; ++i) dot += x[i] * w0[i] + x[4+i] * w1[i];
#pragma unroll
    for (int off = 32; off; off >>= 1) dot += __shfl_xor(dot, off);
    if (lane == 0) {
      const u32* m32 = (const u32*)mask_raw;
      const bool is32 = (m32[448] != 0);
      const bool mk = is32 ? (m32[row] != 0)
                           : (((const unsigned char*)mask_raw)[row] != 0);
      tvec[row] = mk ? -1e30f : (dot + bqbk[0]);
    }
    h8 o;
#pragma unroll
    for (int i = 0; i < 8; ++i) o[i] = (_Float16)x[i];
    *(h8*)(kp + (size_t)row * 512 + d0) = o;
  } else {                               // cvec: 8 rows/block from WoT
    const int row = (bid - 4104) * 8 + wid;
    const float* p = WoT + (size_t)row * 512 + lane * 8;
    const f4v a = *(const f4v*)p, c = *(const f4v*)(p + 4);
    const f4v b0 = *(const f4v*)(bv + lane * 8), b1 = *(const f4v*)(bv + lane * 8 + 4);
    float d = a[0]*b0[0]+a[1]*b0[1]+a[2]*b0[2]+a[3]*b0[3]
            + c[0]*b1[0]+c[1]*b1[1]+c[2]*b1[2]+c[3]*b1[3];
#pragma unroll
    for (int off = 32; off; off >>= 1) d += __shfl_xor(d, off);
    if (lane == 0) cvec[row] = SCALE * d + bo[row];
  }
}

// ---------------- mk + pv merged (counted-vmcnt pipelines) ----------------
__global__ __launch_bounds__(512, 1) void k_mkpv(
    const _Float16* __restrict__ kp, const _Float16* __restrict__ Mm,
    const float* __restrict__ values, const _Float16* __restrict__ Nt,
    _Float16* __restrict__ MKt, _Float16* __restrict__ Pt) {
  __shared__ char lds[122880];
  const int bid = blockIdx.x, tid = threadIdx.x;
  const int lane = tid & 63, wid = tid >> 6;
  const int wr = wid >> 2, wc = wid & 3;
  const int l15 = lane & 15, hi = lane >> 4;
  f4v acc[4][8] = {};
  if (bid < 256) {                       // MKt[t][c] = kp @ Mm^T
    const int tt = bid & 3, b = bid >> 2;
    const _Float16* As = kp + ((size_t)b * TKN + tt * 128) * 512;
    GLD_PIPELINE(As, Mm, acc);
    _Float16* Ob = MKt + (size_t)b * TKN * 512 + (size_t)tt * 128 * 512;
#pragma unroll
    for (int mi = 0; mi < 4; ++mi)
#pragma unroll
      for (int nj = 0; nj < 8; ++nj) {
        const int col = wc * 128 + nj * 16 + l15;
#pragma unroll
        for (int j = 0; j < 4; ++j) {
          const int row = wr * 64 + mi * 16 + hi * 4 + j;
          Ob[(size_t)row * 512 + col] = (_Float16)acc[mi][nj][j];
        }
      }
  } else {                               // Pt[e][t] = (values @ N)^T
    const int rt = (bid - 256) & 3, b = (bid - 256) >> 2;
    const float* As = values + ((size_t)b * TKN + rt * 128) * 512;
    const float* Ad = nullptr;
    REG_PIPELINE(As, Ad, Nt, acc);
    _Float16* Pb = Pt + (size_t)b * 512 * 512;
#pragma unroll
    for (int mi = 0; mi < 4; ++mi)
#pragma unroll
      for (int nj = 0; nj < 8; ++nj) {
        const int col = wc * 128 + nj * 16 + l15;
        const int t0  = rt * 128 + wr * 64 + mi * 16 + hi * 4;
        h4 o;
#pragma unroll
        for (int j = 0; j < 4; ++j) o[j] = (_Float16)acc[mi][nj][j];
        *(h4*)(Pb + (size_t)col * 512 + t0) = o;
      }
  }
}

// ---------------- fused: scores + softmax + attn-write + out-GEMM ----------------
// Phase 1 is byte-identical to the passing round-7 k_scores (standard col mapping).
__global__ __launch_bounds__(512, 1) void k_out(
    const float* __restrict__ query, const float* __restrict__ PEQ,
    const _Float16* __restrict__ MKt, const float* __restrict__ tve,
    const _Float16* __restrict__ Pt, const float* __restrict__ cvec,
    float* __restrict__ attn, float* __restrict__ outp) {
  __shared__ char lds[114688];
  const int tid = threadIdx.x, lane = tid & 63, wid = tid >> 6;
  const int wr = wid >> 2, wc = wid & 3;
  // XCD swizzle: 8 qt-blocks of one batch co-resident on one XCD
  const int bid = blockIdx.x;
  const int xcd = bid & 7, i = bid >> 3;
  const int qt = i & 7, b = xcd * 8 + (i >> 3);
  const float* As = query + ((size_t)b * TQ + qt * 128) * 512;
  const float* Ad = PEQ + (size_t)(qt * 128) * 512;
  const _Float16* Bs = MKt + (size_t)b * TKN * 512;
  const _Float16* PtB = Pt + (size_t)b * 512 * 512;
  const int l15 = lane & 15, hi = lane >> 4;
  float tv[8];
#pragma unroll
  for (int nj = 0; nj < 8; ++nj) tv[nj] = tve[b * TKN + wc * 128 + nj * 16 + l15];

  // ---- phase 1: scores = (q+pe) @ MKt^T ----
  f4v acc[4][8] = {};
  REG_PIPELINE(As, Ad, Bs, acc);

  // ---- fused softmax over full 512-wide rows (round-7 structure) ----
  float* red  = (float*)lds;            // [128][4]  (dead A0 region)
  float* red2 = (float*)(lds + 2048);
#pragma unroll
  for (int mi = 0; mi < 4; ++mi)
#pragma unroll
    for (int nj = 0; nj < 8; ++nj) {
      const float t = tv[nj];
#pragma unroll
      for (int j = 0; j < 4; ++j) acc[mi][nj][j] += t;
    }
  float mrow[4][4];
#pragma unroll
  for (int mi = 0; mi < 4; ++mi)
#pragma unroll
    for (int j = 0; j < 4; ++j) {
      float m = acc[mi][0][j];
#pragma unroll
      for (int nj = 1; nj < 8; ++nj) m = fmaxf(m, acc[mi][nj][j]);
      m = fmaxf(m, __shfl_xor(m, 1)); m = fmaxf(m, __shfl_xor(m, 2));
      m = fmaxf(m, __shfl_xor(m, 4)); m = fmaxf(m, __shfl_xor(m, 8));
      mrow[mi][j] = m;
    }
  __syncthreads();                      // phase-1 LDS reads done before reuse
  if (l15 == 0) {
#pragma unroll
    for (int mi = 0; mi < 4; ++mi)
#pragma unroll
      for (int j = 0; j < 4; ++j)
        red[(wr * 64 + mi * 16 + hi * 4 + j) * 4 + wc] = mrow[mi][j];
  }
  __syncthreads();
#pragma unroll
  for (int mi = 0; mi < 4; ++mi)
#pragma unroll
    for (int j = 0; j < 4; ++j) {
      const f4v rv = *(const f4v*)(red + (wr * 64 + mi * 16 + hi * 4 + j) * 4);
      mrow[mi][j] = fmaxf(fmaxf(rv[0], rv[1]), fmaxf(rv[2], rv[3]));
    }
  float srow[4][4];
#pragma unroll
  for (int mi = 0; mi < 4; ++mi)
#pragma unroll
    for (int j = 0; j < 4; ++j) {
      float s = 0.f;
      const float m = mrow[mi][j];
#pragma unroll
      for (int nj = 0; nj < 8; ++nj) {
        const float e = expf(acc[mi][nj][j] - m);
        acc[mi][nj][j] = e; s += e;
      }
      s += __shfl_xor(s, 1); s += __shfl_xor(s, 2);
      s += __shfl_xor(s, 4); s += __shfl_xor(s, 8);
      srow[mi][j] = s;
    }
  if (l15 == 0) {
#pragma unroll
    for (int mi = 0; mi < 4; ++mi)
#pragma unroll
      for (int j = 0; j < 4; ++j)
        red2[(wr * 64 + mi * 16 + hi * 4 + j) * 4 + wc] = srow[mi][j];
  }
  __syncthreads();

  // ---- attn write + fp16 pk capture (standard col mapping) ----
  float* Ao = attn + ((size_t)b * TQ + qt * 128) * 512;
  h4 pk[4][8];
#pragma unroll
  for (int mi = 0; mi < 4; ++mi)
#pragma unroll
    for (int j = 0; j < 4; ++j) {
      const int row = wr * 64 + mi * 16 + hi * 4 + j;
      const f4v sv = *(const f4v*)(red2 + row * 4);
      const float rinv = 1.f / (sv[0] + sv[1] + sv[2] + sv[3]);
#pragma unroll
      for (int nj = 0; nj < 8; ++nj) {
        const float v = acc[mi][nj][j] * rinv;
        Ao[(size_t)row * 512 + wc * 128 + nj * 16 + l15] = v;
        pk[mi][nj][j] = (_Float16)v;
      }
    }

  // ---- phase 2: out = SCALE * P @ Pt^T + cvec ----
  // P half h = cols [h*256, h*256+256): owned by waves with (wc>>1)==h.
  // Sub-tile sl = (wc&1)*4 + (nj>>1); col-within-tile c32 = ((nj&1)<<4)|l15.
  // Staging uses plain __syncthreads (vmcnt(0)-before-barrier semantics).
  f4v oacc[4][8] = {};
  char* const Ptb1 = lds + 65536;       // single 32KB Pt buffer
#pragma unroll
  for (int h = 0; h < 2; ++h) {
    __syncthreads();                    // previous-half P reads complete
    if ((wc >> 1) == h) {
#pragma unroll
      for (int nj = 0; nj < 8; ++nj) {
        const int sl  = ((wc & 1) << 2) + (nj >> 1);
        const int c32 = ((nj & 1) << 4) | l15;
#pragma unroll
        for (int mi = 0; mi < 4; ++mi)
#pragma unroll
          for (int j = 0; j < 4; ++j) {
            const int r = wr * 64 + mi * 16 + hi * 4 + j;
            const int addr = sl * 8192 + (r << 6)
                           + (((c32 >> 3) ^ ((r >> 1) & 3)) << 4) + ((c32 & 7) << 1);
            *(_Float16*)(lds + addr) = pk[mi][nj][j];
          }
      }
    }
#pragma unroll
    for (int sl = 0; sl < 8; ++sl) {
      const int s = h * 8 + sl;
      stage_B(Ptb1, PtB, s * 32, tid);
      __syncthreads();                  // drains vmcnt(0) + publishes P repack / Pt tile
      h8 pa[4], pb[8];
      read_fragsA(lds + sl * 8192, wr, lane, pa);
      read_fragsB(Ptb1, wc, lane, pb);
      MFMA_ALL(pa, pb, oacc);
      __syncthreads();                  // reads done before next stage overwrites Ptb1
    }
  }
  float cv[8];
#pragma unroll
  for (int nj = 0; nj < 8; ++nj) cv[nj] = cvec[wc * 128 + nj * 16 + l15];
  float* Ob = outp + ((size_t)b * TQ + qt * 128) * 512;
#pragma unroll
  for (int mi = 0; mi < 4; ++mi)
#pragma unroll
    for (int nj = 0; nj < 8; ++nj) {
      const int col = wc * 128 + nj * 16 + l15;
#pragma unroll
      for (int j = 0; j < 4; ++j) {
        const int row = wr * 64 + mi * 16 + hi * 4 + j;
        Ob[(size_t)row * 512 + col] = SCALE * oacc[mi][nj][j] + cv[nj];
      }
    }
}

// ---------------- launcher ----------------
extern "C" void kernel_launch(void* const* d_in, const int* in_sizes, int n_in,
                              void* d_out, int out_size, void* d_ws, size_t ws_size,
                              hipStream_t stream) {
  (void)in_sizes; (void)n_in; (void)out_size;
  if (ws_size < WS_NEED) return;

  const float* query  = (const float*)d_in[0];
  const float* keys   = (const float*)d_in[1];
  const float* values = (const float*)d_in[2];
  const void*  tpos   = d_in[3];
  const void*  fpos   = d_in[4];
  const void*  mask   = d_in[5];
  const float* Wq = (const float*)d_in[6];
  const float* bq = (const float*)d_in[7];
  const float* Wk = (const float*)d_in[8];
  const float* bk = (const float*)d_in[9];
  const float* Wv = (const float*)d_in[10];
  const float* bv = (const float*)d_in[11];
  const float* Wo = (const float*)d_in[12];
  const float* bo = (const float*)d_in[13];

  char* ws = (char*)d_ws;
  _Float16* Mm   = (_Float16*)(ws + OFF_MM);
  _Float16* Nt   = (_Float16*)(ws + OFF_NT);
  float*    WoT  = (float*)   (ws + OFF_WOT);
  float*    PEQ  = (float*)   (ws + OFF_PEQ);
  float*    wvec = (float*)   (ws + OFF_W);
  float*    cvec = (float*)   (ws + OFF_C);
  float*    bqbk = (float*)   (ws + OFF_BQBK);
  float*    tvec = (float*)   (ws + OFF_T);
  _Float16* kp   = (_Float16*)(ws + OFF_KP);
  _Float16* MKt  = (_Float16*)(ws + OFF_MKT);
  _Float16* Pt   = (_Float16*)(ws + OFF_PT);

  float* outp = (float*)d_out;
  float* attn = outp + (size_t)64 * TQ * 512;   // output 1 region

  k_prepA<<<2433, 256, 0, stream>>>(Wk, bq, bk, Wo, fpos, wvec, bqbk, PEQ, WoT);
  k_prepB<<<4168, 512, 0, stream>>>(Wq, Wk, WoT, Wv, keys, tpos, mask,
                                    wvec, bqbk, bv, bo, Mm, Nt, kp, tvec, cvec);
  k_mkpv <<<512, 512, 0, stream>>>(kp, Mm, values, Nt, MKt, Pt);
  k_out  <<<512, 512, 0, stream>>>(query, PEQ, MKt, tvec, Pt, cvec, attn, outp);
}

// Round 12
// 343.100 us; speedup vs baseline: 1.1873x; 1.1873x over previous
//
#include <hip/hip_runtime.h>
#include <stdint.h>

#define DEVI __device__ __forceinline__

typedef __attribute__((ext_vector_type(4))) float     f4v;
typedef __attribute__((ext_vector_type(8))) _Float16  h8;
typedef __attribute__((ext_vector_type(4))) _Float16  h4;
typedef unsigned int  u32;

static constexpr int   TQ = 1024, TKN = 512;
static constexpr float KEY_RATE = 1.385f;
static constexpr float QRY_RATE = 1.0f;
static constexpr float SCALE    = 0.04419417382415922f;   // sqrt(1/512)
static constexpr float INVC     = 0.05190512648261504f;   // log2(10000)/256

// ---------------- workspace layout (bytes) ----------------
static constexpr size_t OFF_MM   = 0;                                  // fp16 [512][512]  Mm = Wq Wk^T
static constexpr size_t OFF_NT   = OFF_MM  + (size_t)512*512*2;        // fp16 [512][512]  Nt = (Wv Wo)^T
static constexpr size_t OFF_WOT  = OFF_NT  + (size_t)512*512*2;        // f32  [512][512]  Wo^T
static constexpr size_t OFF_PEQ  = OFF_WOT + (size_t)512*512*4;        // f32  [1024][512]
static constexpr size_t OFF_W    = OFF_PEQ + (size_t)1024*512*4;       // f32  [512]
static constexpr size_t OFF_C    = OFF_W   + 2048;                     // f32  [512]
static constexpr size_t OFF_BQBK = OFF_C   + 2048;                     // f32  [1]
static constexpr size_t OFF_T    = OFF_BQBK + 256;                     // f32  [64][512] tvec_eff
static constexpr size_t OFF_KP   = OFF_T   + (size_t)64*512*4;         // fp16 [64][512][512] k' = keys+pe
static constexpr size_t OFF_MKT  = OFF_KP  + (size_t)64*512*512*2;     // fp16 [64][512][512] MKt[t][c]
static constexpr size_t OFF_PT   = OFF_MKT + (size_t)64*512*512*2;     // fp16 [64][512][512] Pt[e][t]
static constexpr size_t WS_NEED  = OFF_PT  + (size_t)64*512*512*2;     // ~105 MB
static constexpr size_t OFF_A16  = WS_NEED;                            // fp16 [64][1024][512] attn fp16
static constexpr size_t WS_BIG   = OFF_A16 + (size_t)64*1024*512*2;    // ~206 MB

// ---------------- core helpers: BM=64, BN=512, BK=32, 4 waves / 256 threads ----------------
DEVI f4v mfma16(h8 a, h8 b, f4v c) {
  return __builtin_amdgcn_mfma_f32_16x16x32_f16(a, b, c, 0, 0, 0);
}

DEVI void gld16(void* lds, const void* g) {
  __builtin_amdgcn_global_load_lds(
      (const __attribute__((address_space(1))) unsigned int*)g,
      (__attribute__((address_space(3))) unsigned int*)lds, 16, 0, 0);
}

// B panel: 512 rows x 32 cols fp16 (row stride 512): slot s holds chunk s^((r>>1)&3). 8 gld16/thread (256 thr).
DEVI void stage_B(char* Bbuf, const _Float16* B, int k0, int tid) {
#pragma unroll
  for (int it = 0; it < 8; ++it) {
    const int c = (it << 8) + tid;              // 0..2047 16B chunks
    const int r = c >> 2, s = c & 3;
    const int sg = s ^ ((r >> 1) & 3);
    gld16(Bbuf + ((size_t)c << 4), B + (size_t)r * 512 + k0 + (sg << 3));
  }
}

// A tile fp16: 64 rows x 32 cols (row stride 512). 1 gld16/thread (256 thr).
DEVI void stage_A16(char* Abuf, const _Float16* A, int k0, int tid) {
  const int r = tid >> 2, s = tid & 3;
  const int sg = s ^ ((r >> 1) & 3);
  gld16(Abuf + ((size_t)tid << 4), A + (size_t)r * 512 + k0 + (sg << 3));
}

// A tile fp32 source (64 rows): issue loads (early) ...
DEVI void loads_A32(f4v& x0, f4v& x1, const float* A, const float* add, int k0, int tid) {
  const int r = tid >> 2, c8 = (tid & 3) << 3;
  const float* p = A + (size_t)r * 512 + k0 + c8;
  x0 = *(const f4v*)p; x1 = *(const f4v*)(p + 4);
  if (add) {
    const float* q = add + (size_t)r * 512 + k0 + c8;
    x0 += *(const f4v*)q; x1 += *(const f4v*)(q + 4);
  }
}
// ... convert+write (late)
DEVI void write_A32(char* Abuf, f4v x0, f4v x1, int tid) {
  const int r = tid >> 2;
  const int slot = (tid & 3) ^ ((r >> 1) & 3);
  h8 o;
#pragma unroll
  for (int i = 0; i < 4; ++i) { o[i] = (_Float16)x0[i]; o[4 + i] = (_Float16)x1[i]; }
  *(h8*)(Abuf + (r << 6) + (slot << 4)) = o;
}

DEVI void read_fragsA(const char* Ab, int wr, int lane, h8 (&a)[4]) {
  const int l15 = lane & 15, hi = lane >> 4;
#pragma unroll
  for (int mi = 0; mi < 4; ++mi) {
    const int r = wr * 64 + mi * 16 + l15;
    a[mi] = *(const h8*)(Ab + (r << 6) + ((hi ^ ((r >> 1) & 3)) << 4));
  }
}
DEVI void read_fragsB(const char* Bb, int wc, int lane, h8 (&b)[8]) {
  const int l15 = lane & 15, hi = lane >> 4;
#pragma unroll
  for (int nj = 0; nj < 8; ++nj) {
    const int g = wc * 128 + nj * 16 + l15;
    b[nj] = *(const h8*)(Bb + (g << 6) + ((hi ^ ((g >> 1) & 3)) << 4));
  }
}

#define MFMA_ALL(a, bf, acc)                                   \
  _Pragma("unroll") for (int mi = 0; mi < 4; ++mi)             \
  _Pragma("unroll") for (int nj = 0; nj < 8; ++nj)             \
      acc[mi][nj] = mfma16(a[mi], bf[nj], acc[mi][nj]);

// ---- REG-A 1-ahead pipeline (4 waves): A0@0, A1@4K, B0@8K, B1@40K  (72KB) ----
#define REG_PIPELINE(As, Ad, Bs, acc)                                              \
  {                                                                                \
    char* const Abf[2] = {lds, lds + 4096};                                        \
    char* const Bbf[2] = {lds + 8192, lds + 40960};                                \
    f4v x0, x1;                                                                    \
    loads_A32(x0, x1, As, Ad, 0, tid);                                             \
    stage_B(Bbf[0], Bs, 0, tid);                                                   \
    write_A32(Abf[0], x0, x1, tid);                                                \
    __syncthreads();                                                               \
    _Pragma("unroll")                                                              \
    for (int k = 0; k < 16; ++k) {                                                 \
      if (k < 15) {                                                                \
        loads_A32(x0, x1, As, Ad, (k + 1) * 32, tid);                              \
        stage_B(Bbf[(k + 1) & 1], Bs, (k + 1) * 32, tid);                          \
      }                                                                            \
      h8 a[4], bf[8];                                                              \
      read_fragsA(Abf[k & 1], 0, lane, a);                                         \
      read_fragsB(Bbf[k & 1], wc, lane, bf);                                       \
      MFMA_ALL(a, bf, acc);                                                        \
      if (k < 15) {                                                                \
        write_A32(Abf[(k + 1) & 1], x0, x1, tid);                                  \
        __syncthreads();                                                           \
      }                                                                            \
    }                                                                              \
  }

// ---- GLD-A 1-ahead pipeline (4 waves): A0@0, A1@4K, B0@8K, B1@40K  (72KB) ----
#define GLD_PIPELINE(As, Bs, acc)                                                  \
  {                                                                                \
    char* const Abf[2] = {lds, lds + 4096};                                        \
    char* const Bbf[2] = {lds + 8192, lds + 40960};                                \
    stage_A16(Abf[0], As, 0, tid);                                                 \
    stage_B(Bbf[0], Bs, 0, tid);                                                   \
    __syncthreads();                                                               \
    _Pragma("unroll")                                                              \
    for (int k = 0; k < 16; ++k) {                                                 \
      if (k < 15) {                                                                \
        stage_A16(Abf[(k + 1) & 1], As, (k + 1) * 32, tid);                        \
        stage_B(Bbf[(k + 1) & 1], Bs, (k + 1) * 32, tid);                          \
      }                                                                            \
      h8 a[4], bf[8];                                                              \
      read_fragsA(Abf[k & 1], 0, lane, a);                                         \
      read_fragsB(Bbf[k & 1], wc, lane, bf);                                       \
      MFMA_ALL(a, bf, acc);                                                        \
      if (k < 15) __syncthreads();                                                 \
    }                                                                              \
  }

// reg-stage f32 tiles for the tiny weight-product GEMM (512 threads, 128-row tiles)
DEVI void stage_f32_A(char* Abuf, const float* A, int k0, int tid) {
#pragma unroll
  for (int it = 0; it < 2; ++it) {
    const int idx = (it << 9) + tid;
    const int r = idx >> 3, c4 = idx & 7;
    f4v x = *(const f4v*)(A + (size_t)r * 512 + k0 + (c4 << 2));
    h4 o;
#pragma unroll
    for (int i = 0; i < 4; ++i) o[i] = (_Float16)x[i];
    const int slot = (c4 >> 1) ^ ((r >> 1) & 3);
    *(h4*)(Abuf + (r << 6) + (slot << 4) + ((c4 & 1) << 3)) = o;
  }
}
DEVI void stage_f32_B(char* Bbuf, const float* B, int k0, int tid) {
#pragma unroll
  for (int it = 0; it < 8; ++it) {
    const int idx = (it << 9) + tid;
    const int r = idx >> 3, c4 = idx & 7;
    f4v x = *(const f4v*)(B + (size_t)r * 512 + k0 + (c4 << 2));
    h4 o;
#pragma unroll
    for (int i = 0; i < 4; ++i) o[i] = (_Float16)x[i];
    const int slot = (c4 >> 1) ^ ((r >> 1) & 3);
    *(h4*)(Bbuf + (r << 6) + (slot << 4) + ((c4 & 1) << 3)) = o;
  }
}

// ---------------- prepA: wvec/bqbk + PEQ + Wo^T  (256 threads) ----------------
__global__ __launch_bounds__(256) void k_prepA(
    const float* __restrict__ Wk, const float* __restrict__ bq,
    const float* __restrict__ bk,
    const float* __restrict__ Wo,
    const void* __restrict__ fpos_raw,
    float* __restrict__ wvec, float* __restrict__ bqbk,
    float* __restrict__ PEQ, float* __restrict__ WoT) {
  const int bid = blockIdx.x, tid = threadIdx.x;
  if (bid < 128) {                       // wvec: 4 rows/block, 1 per wave
    const int wid = tid >> 6, lane = tid & 63;
    const int row = bid * 4 + wid;
    const float* p = Wk + (size_t)row * 512 + lane * 8;
    const f4v a = *(const f4v*)p, c = *(const f4v*)(p + 4);
    const f4v b0 = *(const f4v*)(bq + lane * 8), b1 = *(const f4v*)(bq + lane * 8 + 4);
    float d = a[0]*b0[0]+a[1]*b0[1]+a[2]*b0[2]+a[3]*b0[3]
            + c[0]*b1[0]+c[1]*b1[1]+c[2]*b1[2]+c[3]*b1[3];
#pragma unroll
    for (int off = 32; off; off >>= 1) d += __shfl_xor(d, off);
    if (lane == 0) wvec[row] = d;
  } else if (bid == 128) {               // bqbk
    __shared__ float red[256];
    red[tid] = bq[tid] * bk[tid] + bq[tid + 256] * bk[tid + 256];
    __syncthreads();
    if (tid == 0) { float s = 0.f; for (int h = 0; h < 256; ++h) s += red[h]; bqbk[0] = s; }
  } else if (bid < 129 + 2048) {         // PEQ
    const u32* fp = (const u32*)fpos_raw;
    const bool is64 = (fp[1] == 0);
    const int t = (bid - 129) * 256 + tid;
    const int tq = t >> 9, d = t & 511;
    const int pos = (int)(is64 ? fp[2 * tq] : fp[tq]);
    float pe = 0.f;
    if (pos != 0) {
      const float invf = exp2f(-(float)(d >> 1) * INVC);
      const float ang  = ((float)pos * QRY_RATE) * invf;
      pe = (d & 1) ? cosf(ang) : sinf(ang);
    }
    PEQ[t] = pe;
  } else {                               // Wo^T 32x32 tiles
    __shared__ float t[32][33];
    const int local = bid - 2177;
    const int bx = local & 15, by = local >> 4;
    const int tx = tid & 31, ty = tid >> 5;
    const int x = bx * 32 + tx;
#pragma unroll
    for (int j = 0; j < 4; ++j)
      t[ty + 8 * j][tx] = Wo[(size_t)(by * 32 + ty + 8 * j) * 512 + x];
    __syncthreads();
    const int x2 = by * 32 + tx;
#pragma unroll
    for (int j = 0; j < 4; ++j)
      WoT[(size_t)(bx * 32 + ty + 8 * j) * 512 + x2] = t[tx][ty + 8 * j];
  }
}

// ---------------- prepB: weight-product GEMMs + key prep + cvec  (512 threads) ----------------
__global__ __launch_bounds__(512) void k_prepB(
    const float* __restrict__ Wq, const float* __restrict__ Wk,
    const float* __restrict__ WoT, const float* __restrict__ Wv,
    const float* __restrict__ keys, const void* __restrict__ tpos_raw,
    const void* __restrict__ mask_raw,
    const float* __restrict__ wvec, const float* __restrict__ bqbk,
    const float* __restrict__ bv, const float* __restrict__ bo,
    _Float16* __restrict__ Mm, _Float16* __restrict__ Nt,
    _Float16* __restrict__ kp, float* __restrict__ tvec,
    float* __restrict__ cvec) {
  __shared__ char lds[40960];
  const int bid = blockIdx.x, tid = threadIdx.x;
  const int lane = tid & 63, wid = tid >> 6;
  if (bid < 8) {                         // weight products (128-row tiles, 8 waves)
    char *Ab = lds, *Bb = lds + 8192;
    const int wr = wid >> 2, wc = wid & 3;
    const int x = bid & 3, y = bid >> 2;
    const float* A = (y == 0 ? Wq : WoT) + (size_t)x * 128 * 512;
    const float* B = (y == 0 ? Wk : Wv);
    _Float16* out = (y == 0 ? Mm : Nt) + (size_t)x * 128 * 512;
    f4v acc[4][8] = {};
    for (int ks = 0; ks < 16; ++ks) {
      stage_f32_A(Ab, A, ks * 32, tid);
      stage_f32_B(Bb, B, ks * 32, tid);
      __syncthreads();
      h8 a[4], bf[8];
      read_fragsA(Ab, wr, lane, a);
      read_fragsB(Bb, wc, lane, bf);
      MFMA_ALL(a, bf, acc);
      __syncthreads();
    }
    const int l15 = lane & 15, hi = lane >> 4;
#pragma unroll
    for (int mi = 0; mi < 4; ++mi)
#pragma unroll
      for (int nj = 0; nj < 8; ++nj) {
        const int col = wc * 128 + nj * 16 + l15;
#pragma unroll
        for (int j = 0; j < 4; ++j) {
          const int row = wr * 64 + mi * 16 + hi * 4 + j;
          out[(size_t)row * 512 + col] = (_Float16)acc[mi][nj][j];
        }
      }
  } else if (bid < 4104) {               // key prep: 8 rows/block
    const u32* tp = (const u32*)tpos_raw;
    const bool is64 = (tp[1] == 0);
    const int row = (bid - 8) * 8 + wid;
    const int pos = (int)(is64 ? tp[2 * row] : tp[row]);
    const int d0  = lane * 8;
    const float* src = keys + (size_t)row * 512 + d0;
    const f4v a = *(const f4v*)src, b = *(const f4v*)(src + 4);
    float x[8] = {a[0], a[1], a[2], a[3], b[0], b[1], b[2], b[3]};
    if (pos != 0) {
      const float pw = (float)pos * KEY_RATE;
#pragma unroll
      for (int u = 0; u < 4; ++u) {
        const float invf = exp2f(-(float)(lane * 4 + u) * INVC);
        const float ang  = pw * invf;
        x[2*u]   += sinf(ang);
        x[2*u+1] += cosf(ang);
      }
    }
    const f4v w0 = *(const f4v*)(wvec + d0), w1 = *(const f4v*)(wvec + d0 + 4);
    float dot = 0.f;
#pragma unroll
    for (int i = 0; i < 4; ++i) dot += x[i] * w0[i] + x[4+i] * w1[i];
#pragma unroll
    for (int off = 32; off; off >>= 1) dot += __shfl_xor(dot, off);
    if (lane == 0) {
      const u32* m32 = (const u32*)mask_raw;
      const bool is32 = (m32[448] != 0);
      const bool mk = is32 ? (m32[row] != 0)
                           : (((const unsigned char*)mask_raw)[row] != 0);
      tvec[row] = mk ? -1e30f : (dot + bqbk[0]);
    }
    h8 o;
#pragma unroll
    for (int i = 0; i < 8; ++i) o[i] = (_Float16)x[i];
    *(h8*)(kp + (size_t)row * 512 + d0) = o;
  } else {                               // cvec: 8 rows/block from WoT
    const int row = (bid - 4104) * 8 + wid;
    const float* p = WoT + (size_t)row * 512 + lane * 8;
    const f4v a = *(const f4v*)p, c = *(const f4v*)(p + 4);
    const f4v b0 = *(const f4v*)(bv + lane * 8), b1 = *(const f4v*)(bv + lane * 8 + 4);
    float d = a[0]*b0[0]+a[1]*b0[1]+a[2]*b0[2]+a[3]*b0[3]
            + c[0]*b1[0]+c[1]*b1[1]+c[2]*b1[2]+c[3]*b1[3];
#pragma unroll
    for (int off = 32; off; off >>= 1) d += __shfl_xor(d, off);
    if (lane == 0) cvec[row] = SCALE * d + bo[row];
  }
}

// ---------------- mk + pv merged (256 threads, 64-row tiles, 2 blocks/CU) ----------------
__global__ __launch_bounds__(256, 2) void k_mkpv(
    const _Float16* __restrict__ kp, const _Float16* __restrict__ Mm,
    const float* __restrict__ values, const _Float16* __restrict__ Nt,
    _Float16* __restrict__ MKt, _Float16* __restrict__ Pt) {
  __shared__ char lds[73728];
  const int bid = blockIdx.x, tid = threadIdx.x;
  const int lane = tid & 63, wc = (tid >> 6) & 3;
  const int l15 = lane & 15, hi = lane >> 4;
  f4v acc[4][8] = {};
  if (bid < 512) {                       // MKt[t][c] = kp @ Mm^T
    const int tt = bid & 7, b = bid >> 3;
    const _Float16* As = kp + ((size_t)b * TKN + tt * 64) * 512;
    GLD_PIPELINE(As, Mm, acc);
    _Float16* Ob = MKt + (size_t)b * TKN * 512 + (size_t)tt * 64 * 512;
#pragma unroll
    for (int mi = 0; mi < 4; ++mi)
#pragma unroll
      for (int nj = 0; nj < 8; ++nj) {
        const int col = wc * 128 + nj * 16 + l15;
#pragma unroll
        for (int j = 0; j < 4; ++j) {
          const int row = mi * 16 + hi * 4 + j;
          Ob[(size_t)row * 512 + col] = (_Float16)acc[mi][nj][j];
        }
      }
  } else {                               // Pt[e][t] = (values @ N)^T
    const int idx = bid - 512;
    const int rt = idx & 7, b = idx >> 3;
    const float* As = values + ((size_t)b * TKN + rt * 64) * 512;
    const float* Ad = nullptr;
    REG_PIPELINE(As, Ad, Nt, acc);
    _Float16* Pb = Pt + (size_t)b * 512 * 512;
#pragma unroll
    for (int mi = 0; mi < 4; ++mi)
#pragma unroll
      for (int nj = 0; nj < 8; ++nj) {
        const int col = wc * 128 + nj * 16 + l15;
        const int t0  = rt * 64 + mi * 16 + hi * 4;
        h4 o;
#pragma unroll
        for (int j = 0; j < 4; ++j) o[j] = (_Float16)acc[mi][nj][j];
        *(h4*)(Pb + (size_t)col * 512 + t0) = o;
      }
  }
}

// ---------------- scores + fused softmax (256 threads, 64-row tiles, XCD-local) ----------------
__global__ __launch_bounds__(256, 2) void k_scores(
    const float* __restrict__ query, const float* __restrict__ PEQ,
    const _Float16* __restrict__ MKt, const float* __restrict__ tve,
    float* __restrict__ attn, _Float16* __restrict__ a16) {
  __shared__ char lds[73728];
  const int tid = threadIdx.x, lane = tid & 63, wc = (tid >> 6) & 3;
  const int bid = blockIdx.x;
  const int xcd = bid & 7, i = bid >> 3;
  const int qt = i & 15, b = xcd * 8 + (i >> 4);
  const float* As = query + ((size_t)b * TQ + qt * 64) * 512;
  const float* Ad = PEQ + (size_t)(qt * 64) * 512;
  const _Float16* Bs = MKt + (size_t)b * TKN * 512;
  const int l15 = lane & 15, hi = lane >> 4;
  float tv[8];
#pragma unroll
  for (int nj = 0; nj < 8; ++nj) tv[nj] = tve[b * TKN + wc * 128 + nj * 16 + l15];
  f4v acc[4][8] = {};
  REG_PIPELINE(As, Ad, Bs, acc);
  // ---- fused softmax over full 512-wide rows (red arrays reuse A0/A1 region) ----
  float* red  = (float*)lds;            // [64][4]
  float* red2 = (float*)(lds + 1024);
#pragma unroll
  for (int mi = 0; mi < 4; ++mi)
#pragma unroll
    for (int nj = 0; nj < 8; ++nj) {
      const float t = tv[nj];
#pragma unroll
      for (int j = 0; j < 4; ++j) acc[mi][nj][j] += t;
    }
  float mrow[4][4];
#pragma unroll
  for (int mi = 0; mi < 4; ++mi)
#pragma unroll
    for (int j = 0; j < 4; ++j) {
      float m = acc[mi][0][j];
#pragma unroll
      for (int nj = 1; nj < 8; ++nj) m = fmaxf(m, acc[mi][nj][j]);
      m = fmaxf(m, __shfl_xor(m, 1)); m = fmaxf(m, __shfl_xor(m, 2));
      m = fmaxf(m, __shfl_xor(m, 4)); m = fmaxf(m, __shfl_xor(m, 8));
      mrow[mi][j] = m;
    }
  __syncthreads();                      // phase-1 LDS reads done before reuse
  if (l15 == 0) {
#pragma unroll
    for (int mi = 0; mi < 4; ++mi)
#pragma unroll
      for (int j = 0; j < 4; ++j)
        red[(mi * 16 + hi * 4 + j) * 4 + wc] = mrow[mi][j];
  }
  __syncthreads();
#pragma unroll
  for (int mi = 0; mi < 4; ++mi)
#pragma unroll
    for (int j = 0; j < 4; ++j) {
      const f4v rv = *(const f4v*)(red + (mi * 16 + hi * 4 + j) * 4);
      mrow[mi][j] = fmaxf(fmaxf(rv[0], rv[1]), fmaxf(rv[2], rv[3]));
    }
  float srow[4][4];
#pragma unroll
  for (int mi = 0; mi < 4; ++mi)
#pragma unroll
    for (int j = 0; j < 4; ++j) {
      float s = 0.f;
      const float m = mrow[mi][j];
#pragma unroll
      for (int nj = 0; nj < 8; ++nj) {
        const float e = expf(acc[mi][nj][j] - m);
        acc[mi][nj][j] = e; s += e;
      }
      s += __shfl_xor(s, 1); s += __shfl_xor(s, 2);
      s += __shfl_xor(s, 4); s += __shfl_xor(s, 8);
      srow[mi][j] = s;
    }
  if (l15 == 0) {
#pragma unroll
    for (int mi = 0; mi < 4; ++mi)
#pragma unroll
      for (int j = 0; j < 4; ++j)
        red2[(mi * 16 + hi * 4 + j) * 4 + wc] = srow[mi][j];
  }
  __syncthreads();
  float* Ao = attn + ((size_t)b * TQ + qt * 64) * 512;
  _Float16* Ah = a16 ? a16 + ((size_t)b * TQ + qt * 64) * 512 : nullptr;
#pragma unroll
  for (int mi = 0; mi < 4; ++mi)
#pragma unroll
    for (int j = 0; j < 4; ++j) {
      const int row = mi * 16 + hi * 4 + j;
      const f4v sv = *(const f4v*)(red2 + row * 4);
      const float rinv = 1.f / (sv[0] + sv[1] + sv[2] + sv[3]);
#pragma unroll
      for (int nj = 0; nj < 8; ++nj) {
        const float v = acc[mi][nj][j] * rinv;
        const int col = wc * 128 + nj * 16 + l15;
        Ao[(size_t)row * 512 + col] = v;
        if (Ah) Ah[(size_t)row * 512 + col] = (_Float16)v;
      }
    }
}

// ---------------- out = SCALE * attn @ Pt^T + cvec (256 threads, XCD-local) ----------------
template <int A16P>
__global__ __launch_bounds__(256, 2) void k_final(
    const float* __restrict__ attn, const _Float16* __restrict__ attn16,
    const _Float16* __restrict__ Pt, const float* __restrict__ cvec,
    float* __restrict__ outp) {
  __shared__ char lds[73728];
  const int tid = threadIdx.x, lane = tid & 63, wc = (tid >> 6) & 3;
  const int bid = blockIdx.x;
  const int xcd = bid & 7, i = bid >> 3;
  const int qt = i & 15, b = xcd * 8 + (i >> 4);
  const _Float16* Bs = Pt + (size_t)b * 512 * 512;
  const int l15 = lane & 15, hi = lane >> 4;
  f4v acc[4][8] = {};
  if (A16P) {
    const _Float16* As = attn16 + ((size_t)b * TQ + qt * 64) * 512;
    GLD_PIPELINE(As, Bs, acc);
  } else {
    const float* As = attn + ((size_t)b * TQ + qt * 64) * 512;
    const float* Ad = nullptr;
    REG_PIPELINE(As, Ad, Bs, acc);
  }
  float cv[8];
#pragma unroll
  for (int nj = 0; nj < 8; ++nj) cv[nj] = cvec[wc * 128 + nj * 16 + l15];
  float* Ob = outp + ((size_t)b * TQ + qt * 64) * 512;
#pragma unroll
  for (int mi = 0; mi < 4; ++mi)
#pragma unroll
    for (int nj = 0; nj < 8; ++nj) {
      const int col = wc * 128 + nj * 16 + l15;
#pragma unroll
      for (int j = 0; j < 4; ++j) {
        const int row = mi * 16 + hi * 4 + j;
        Ob[(size_t)row * 512 + col] = SCALE * acc[mi][nj][j] + cv[nj];
      }
    }
}

// ---------------- launcher ----------------
extern "C" void kernel_launch(void* const* d_in, const int* in_sizes, int n_in,
                              void* d_out, int out_size, void* d_ws, size_t ws_size,
                              hipStream_t stream) {
  (void)in_sizes; (void)n_in; (void)out_size;
  if (ws_size < WS_NEED) return;
  const bool big = (ws_size >= WS_BIG);

  const float* query  = (const float*)d_in[0];
  const float* keys   = (const float*)d_in[1];
  const float* values = (const float*)d_in[2];
  const void*  tpos   = d_in[3];
  const void*  fpos   = d_in[4];
  const void*  mask   = d_in[5];
  const float* Wq = (const float*)d_in[6];
  const float* bq = (const float*)d_in[7];
  const float* Wk = (const float*)d_in[8];
  const float* bk = (const float*)d_in[9];
  const float* Wv = (const float*)d_in[10];
  const float* bv = (const float*)d_in[11];
  const float* Wo = (const float*)d_in[12];
  const float* bo = (const float*)d_in[13];

  char* ws = (char*)d_ws;
  _Float16* Mm   = (_Float16*)(ws + OFF_MM);
  _Float16* Nt   = (_Float16*)(ws + OFF_NT);
  float*    WoT  = (float*)   (ws + OFF_WOT);
  float*    PEQ  = (float*)   (ws + OFF_PEQ);
  float*    wvec = (float*)   (ws + OFF_W);
  float*    cvec = (float*)   (ws + OFF_C);
  float*    bqbk = (float*)   (ws + OFF_BQBK);
  float*    tvec = (float*)   (ws + OFF_T);
  _Float16* kp   = (_Float16*)(ws + OFF_KP);
  _Float16* MKt  = (_Float16*)(ws + OFF_MKT);
  _Float16* Pt   = (_Float16*)(ws + OFF_PT);
  _Float16* a16  = big ? (_Float16*)(ws + OFF_A16) : nullptr;

  float* outp = (float*)d_out;
  float* attn = outp + (size_t)64 * TQ * 512;   // output 1 region

  k_prepA<<<2433, 256, 0, stream>>>(Wk, bq, bk, Wo, fpos, wvec, bqbk, PEQ, WoT);
  k_prepB<<<4168, 512, 0, stream>>>(Wq, Wk, WoT, Wv, keys, tpos, mask,
                                    wvec, bqbk, bv, bo, Mm, Nt, kp, tvec, cvec);
  k_mkpv <<<1024, 256, 0, stream>>>(kp, Mm, values, Nt, MKt, Pt);
  k_scores<<<1024, 256, 0, stream>>>(query, PEQ, MKt, tvec, attn, a16);
  if (big) k_final<1><<<1024, 256, 0, stream>>>(attn, a16, Pt, cvec, outp);
  else     k_final<0><<<1024, 256, 0, stream>>>(attn, a16, Pt, cvec, outp);
}

// Round 13
// 299.964 us; speedup vs baseline: 1.3580x; 1.1438x over previous
//
#include <hip/hip_runtime.h>
#include <stdint.h>

#define DEVI __device__ __forceinline__

typedef __attribute__((ext_vector_type(4))) float     f4v;
typedef __attribute__((ext_vector_type(8))) _Float16  h8;
typedef __attribute__((ext_vector_type(4))) _Float16  h4;
typedef unsigned int  u32;

static constexpr int   TQ = 1024, TKN = 512;
static constexpr float KEY_RATE = 1.385f;
static constexpr float QRY_RATE = 1.0f;
static constexpr float SCALE    = 0.04419417382415922f;   // sqrt(1/512)
static constexpr float INVC     = 0.05190512648261504f;   // log2(10000)/256

// ---------------- workspace layout (bytes) ----------------
static constexpr size_t OFF_MM   = 0;                                  // fp16 [512][512]  Mm = Wq Wk^T
static constexpr size_t OFF_NT   = OFF_MM  + (size_t)512*512*2;        // fp16 [512][512]  Nt = (Wv Wo)^T
static constexpr size_t OFF_WOT  = OFF_NT  + (size_t)512*512*2;        // f32  [512][512]  Wo^T
static constexpr size_t OFF_PEQ  = OFF_WOT + (size_t)512*512*4;        // f32  [1024][512]
static constexpr size_t OFF_W    = OFF_PEQ + (size_t)1024*512*4;       // f32  [512]
static constexpr size_t OFF_C    = OFF_W   + 2048;                     // f32  [512]
static constexpr size_t OFF_BQBK = OFF_C   + 2048;                     // f32  [1]
static constexpr size_t OFF_T    = OFF_BQBK + 256;                     // f32  [64][512] tvec_eff
static constexpr size_t OFF_KP   = OFF_T   + (size_t)64*512*4;         // fp16 [64][512][512] k' = keys+pe
static constexpr size_t OFF_MKT  = OFF_KP  + (size_t)64*512*512*2;     // fp16 [64][512][512] MKt[t][c]
static constexpr size_t OFF_PT   = OFF_MKT + (size_t)64*512*512*2;     // fp16 [64][512][512] Pt[e][t]
static constexpr size_t WS_NEED  = OFF_PT  + (size_t)64*512*512*2;     // ~105 MB
static constexpr size_t OFF_A16  = WS_NEED;                            // fp16 [64][1024][512] attn fp16
static constexpr size_t WS_BIG   = OFF_A16 + (size_t)64*1024*512*2;    // ~206 MB

#define WAITV(N) asm volatile("s_waitcnt vmcnt(" #N ")" ::: "memory")
#define WAITL()  asm volatile("s_waitcnt lgkmcnt(0)" ::: "memory")
#define SCHEDB() __builtin_amdgcn_sched_barrier(0)
#define BARRAW() __builtin_amdgcn_s_barrier()

// ---------------- core helpers (BM=128, BN=512, BK=32 template) ----------------
DEVI f4v mfma16(h8 a, h8 b, f4v c) {
  return __builtin_amdgcn_mfma_f32_16x16x32_f16(a, b, c, 0, 0, 0);
}

DEVI void gld16(void* lds, const void* g) {
  __builtin_amdgcn_global_load_lds(
      (const __attribute__((address_space(1))) unsigned int*)g,
      (__attribute__((address_space(3))) unsigned int*)lds, 16, 0, 0);
}

// B panel: 512 rows x 32 cols fp16 (row stride 512): slot s holds chunk s^((r>>1)&3). 4 gld16/thread.
DEVI void stage_B(char* Bbuf, const _Float16* B, int k0, int tid) {
#pragma unroll
  for (int it = 0; it < 4; ++it) {
    const int c = (it << 9) + tid;              // 0..2047 16B chunks
    const int r = c >> 2, s = c & 3;
    const int sg = s ^ ((r >> 1) & 3);
    gld16(Bbuf + ((size_t)c << 4), B + (size_t)r * 512 + k0 + (sg << 3));
  }
}

// A tile fp16: 128 rows x 32 cols (row stride 512). 1 gld16/thread.
DEVI void stage_A16(char* Abuf, const _Float16* A, int k0, int tid) {
  const int r = tid >> 2, s = tid & 3;
  const int sg = s ^ ((r >> 1) & 3);
  gld16(Abuf + ((size_t)tid << 4), A + (size_t)r * 512 + k0 + (sg << 3));
}

// A tile fp32 source: issue loads (early) ...
DEVI void loads_A32(f4v& x0, f4v& x1, const float* A, const float* add, int k0, int tid) {
  const int r = tid >> 2, c8 = (tid & 3) << 3;
  const float* p = A + (size_t)r * 512 + k0 + c8;
  x0 = *(const f4v*)p; x1 = *(const f4v*)(p + 4);
  if (add) {
    const float* q = add + (size_t)r * 512 + k0 + c8;
    x0 += *(const f4v*)q; x1 += *(const f4v*)(q + 4);
  }
}
// ... convert+write (late)
DEVI void write_A32(char* Abuf, f4v x0, f4v x1, int tid) {
  const int r = tid >> 2;
  const int slot = (tid & 3) ^ ((r >> 1) & 3);
  h8 o;
#pragma unroll
  for (int i = 0; i < 4; ++i) { o[i] = (_Float16)x0[i]; o[4 + i] = (_Float16)x1[i]; }
  *(h8*)(Abuf + (r << 6) + (slot << 4)) = o;
}

DEVI void read_fragsA(const char* Ab, int wr, int lane, h8 (&a)[4]) {
  const int l15 = lane & 15, hi = lane >> 4;
#pragma unroll
  for (int mi = 0; mi < 4; ++mi) {
    const int r = wr * 64 + mi * 16 + l15;
    a[mi] = *(const h8*)(Ab + (r << 6) + ((hi ^ ((r >> 1) & 3)) << 4));
  }
}
DEVI void read_fragsB(const char* Bb, int wc, int lane, h8 (&b)[8]) {
  const int l15 = lane & 15, hi = lane >> 4;
#pragma unroll
  for (int nj = 0; nj < 8; ++nj) {
    const int g = wc * 128 + nj * 16 + l15;
    b[nj] = *(const h8*)(Bb + (g << 6) + ((hi ^ ((g >> 1) & 3)) << 4));
  }
}

// T5: setprio around the MFMA cluster (role-split waves within a pipeline step)
#define MFMA_ALL(a, bf, acc) do {                               \
  __builtin_amdgcn_s_setprio(1);                                \
  _Pragma("unroll") for (int mi = 0; mi < 4; ++mi)              \
  _Pragma("unroll") for (int nj = 0; nj < 8; ++nj)              \
      acc[mi][nj] = mfma16(a[mi], bf[nj], acc[mi][nj]);         \
  __builtin_amdgcn_s_setprio(0);                                \
} while (0)

// ---- REG-A pipeline: A f32 (+opt add) reg-staged 2-deep, B gld16 3-deep, counted vmcnt ----
// LDS map: A0@0, A1@8K, B0@16K, B1@48K, B2@80K  (112KB)
#define REG_PIPELINE(As, Ad, Bs, acc)                                              \
  {                                                                                \
    char* const Abf[2] = {lds, lds + 8192};                                        \
    char* const Bbf[3] = {lds + 16384, lds + 49152, lds + 81920};                  \
    f4v xa0, xa1, xb0, xb1;                                                        \
    loads_A32(xa0, xa1, As, Ad, 0, tid);                                           \
    loads_A32(xb0, xb1, As, Ad, 32, tid);                                          \
    SCHEDB();                                                                      \
    stage_B(Bbf[0], Bs, 0, tid);                                                   \
    stage_B(Bbf[1], Bs, 32, tid);                                                  \
    WAITV(4);                                                                      \
    write_A32(Abf[0], xa0, xa1, tid);                                              \
    WAITL(); SCHEDB(); BARRAW(); SCHEDB();                                         \
    _Pragma("unroll")                                                              \
    for (int k = 0; k < 16; ++k) {                                                 \
      if (k < 14) {                                                                \
        if ((k & 1) == 0) { loads_A32(xa0, xa1, As, Ad, (k + 2) * 32, tid); }      \
        else              { loads_A32(xb0, xb1, As, Ad, (k + 2) * 32, tid); }      \
        SCHEDB();                                                                  \
        stage_B(Bbf[(k + 2) % 3], Bs, (k + 2) * 32, tid);                          \
      }                                                                            \
      h8 a[4], bf[8];                                                              \
      read_fragsA(Abf[k & 1], wr, lane, a);                                        \
      read_fragsB(Bbf[k % 3], wc, lane, bf);                                       \
      MFMA_ALL(a, bf, acc);                                                        \
      if (k < 15) {                                                                \
        if (k < 14) { WAITV(6); } else { WAITV(0); }                               \
        if ((k & 1) == 0) write_A32(Abf[1], xb0, xb1, tid);                        \
        else              write_A32(Abf[0], xa0, xa1, tid);                        \
        WAITL(); SCHEDB(); BARRAW(); SCHEDB();                                     \
      }                                                                            \
    }                                                                              \
  }

// ---- GLD-A pipeline loop: A fp16 gld16 3-deep, B gld16 3-deep ----
// LDS map: A0@0, A1@8K, A2@16K, B0@24K, B1@56K, B2@88K  (120KB)
#define GLD_PIPELINE(As, Bs, acc)                                                  \
  {                                                                                \
    char* const Abf[3] = {lds, lds + 8192, lds + 16384};                           \
    char* const Bbf[3] = {lds + 24576, lds + 57344, lds + 90112};                  \
    stage_A16(Abf[0], As, 0, tid);  stage_B(Bbf[0], Bs, 0, tid);                   \
    stage_A16(Abf[1], As, 32, tid); stage_B(Bbf[1], Bs, 32, tid);                  \
    WAITV(5); SCHEDB(); BARRAW(); SCHEDB();                                        \
    _Pragma("unroll")                                                              \
    for (int k = 0; k < 16; ++k) {                                                 \
      if (k < 14) {                                                                \
        stage_A16(Abf[(k + 2) % 3], As, (k + 2) * 32, tid);                        \
        stage_B(Bbf[(k + 2) % 3], Bs, (k + 2) * 32, tid);                          \
      }                                                                            \
      h8 a[4], bf[8];                                                              \
      read_fragsA(Abf[k % 3], wr, lane, a);                                        \
      read_fragsB(Bbf[k % 3], wc, lane, bf);                                       \
      MFMA_ALL(a, bf, acc);                                                        \
      if (k < 14) { WAITV(5); } else if (k == 14) { WAITV(0); }                    \
      if (k < 15) { WAITL(); SCHEDB(); BARRAW(); SCHEDB(); }                       \
    }                                                                              \
  }

// reg-stage f32 tiles for the tiny weight-product GEMM (single-buffered)
DEVI void stage_f32_A(char* Abuf, const float* A, int k0, int tid) {
#pragma unroll
  for (int it = 0; it < 2; ++it) {
    const int idx = (it << 9) + tid;
    const int r = idx >> 3, c4 = idx & 7;
    f4v x = *(const f4v*)(A + (size_t)r * 512 + k0 + (c4 << 2));
    h4 o;
#pragma unroll
    for (int i = 0; i < 4; ++i) o[i] = (_Float16)x[i];
    const int slot = (c4 >> 1) ^ ((r >> 1) & 3);
    *(h4*)(Abuf + (r << 6) + (slot << 4) + ((c4 & 1) << 3)) = o;
  }
}
DEVI void stage_f32_B(char* Bbuf, const float* B, int k0, int tid) {
#pragma unroll
  for (int it = 0; it < 8; ++it) {
    const int idx = (it << 9) + tid;
    const int r = idx >> 3, c4 = idx & 7;
    f4v x = *(const f4v*)(B + (size_t)r * 512 + k0 + (c4 << 2));
    h4 o;
#pragma unroll
    for (int i = 0; i < 4; ++i) o[i] = (_Float16)x[i];
    const int slot = (c4 >> 1) ^ ((r >> 1) & 3);
    *(h4*)(Bbuf + (r << 6) + (slot << 4) + ((c4 & 1) << 3)) = o;
  }
}

// ---------------- prepA: wvec/bqbk + PEQ + Wo^T  (256 threads) ----------------
__global__ __launch_bounds__(256) void k_prepA(
    const float* __restrict__ Wk, const float* __restrict__ bq,
    const float* __restrict__ bk,
    const float* __restrict__ Wo,
    const void* __restrict__ fpos_raw,
    float* __restrict__ wvec, float* __restrict__ bqbk,
    float* __restrict__ PEQ, float* __restrict__ WoT) {
  const int bid = blockIdx.x, tid = threadIdx.x;
  if (bid < 128) {                       // wvec: 4 rows/block, 1 per wave
    const int wid = tid >> 6, lane = tid & 63;
    const int row = bid * 4 + wid;
    const float* p = Wk + (size_t)row * 512 + lane * 8;
    const f4v a = *(const f4v*)p, c = *(const f4v*)(p + 4);
    const f4v b0 = *(const f4v*)(bq + lane * 8), b1 = *(const f4v*)(bq + lane * 8 + 4);
    float d = a[0]*b0[0]+a[1]*b0[1]+a[2]*b0[2]+a[3]*b0[3]
            + c[0]*b1[0]+c[1]*b1[1]+c[2]*b1[2]+c[3]*b1[3];
#pragma unroll
    for (int off = 32; off; off >>= 1) d += __shfl_xor(d, off);
    if (lane == 0) wvec[row] = d;
  } else if (bid == 128) {               // bqbk
    __shared__ float red[256];
    red[tid] = bq[tid] * bk[tid] + bq[tid + 256] * bk[tid + 256];
    __syncthreads();
    if (tid == 0) { float s = 0.f; for (int h = 0; h < 256; ++h) s += red[h]; bqbk[0] = s; }
  } else if (bid < 129 + 2048) {         // PEQ
    const u32* fp = (const u32*)fpos_raw;
    const bool is64 = (fp[1] == 0);
    const int t = (bid - 129) * 256 + tid;
    const int tq = t >> 9, d = t & 511;
    const int pos = (int)(is64 ? fp[2 * tq] : fp[tq]);
    float pe = 0.f;
    if (pos != 0) {
      const float invf = exp2f(-(float)(d >> 1) * INVC);
      const float ang  = ((float)pos * QRY_RATE) * invf;
      pe = (d & 1) ? cosf(ang) : sinf(ang);
    }
    PEQ[t] = pe;
  } else {                               // Wo^T 32x32 tiles
    __shared__ float t[32][33];
    const int local = bid - 2177;
    const int bx = local & 15, by = local >> 4;
    const int tx = tid & 31, ty = tid >> 5;
    const int x = bx * 32 + tx;
#pragma unroll
    for (int j = 0; j < 4; ++j)
      t[ty + 8 * j][tx] = Wo[(size_t)(by * 32 + ty + 8 * j) * 512 + x];
    __syncthreads();
    const int x2 = by * 32 + tx;
#pragma unroll
    for (int j = 0; j < 4; ++j)
      WoT[(size_t)(bx * 32 + ty + 8 * j) * 512 + x2] = t[tx][ty + 8 * j];
  }
}

// ---------------- prepB: weight-product GEMMs + key prep + cvec  (512 threads) ----------------
__global__ __launch_bounds__(512) void k_prepB(
    const float* __restrict__ Wq, const float* __restrict__ Wk,
    const float* __restrict__ WoT, const float* __restrict__ Wv,
    const float* __restrict__ keys, const void* __restrict__ tpos_raw,
    const void* __restrict__ mask_raw,
    const float* __restrict__ wvec, const float* __restrict__ bqbk,
    const float* __restrict__ bv, const float* __restrict__ bo,
    _Float16* __restrict__ Mm, _Float16* __restrict__ Nt,
    _Float16* __restrict__ kp, float* __restrict__ tvec,
    float* __restrict__ cvec) {
  __shared__ char lds[40960];
  const int bid = blockIdx.x, tid = threadIdx.x;
  const int lane = tid & 63, wid = tid >> 6;
  if (bid < 8) {                         // weight products
    char *Ab = lds, *Bb = lds + 8192;
    const int wr = wid >> 2, wc = wid & 3;
    const int x = bid & 3, y = bid >> 2;
    const float* A = (y == 0 ? Wq : WoT) + (size_t)x * 128 * 512;
    const float* B = (y == 0 ? Wk : Wv);
    _Float16* out = (y == 0 ? Mm : Nt) + (size_t)x * 128 * 512;
    f4v acc[4][8] = {};
    for (int ks = 0; ks < 16; ++ks) {
      stage_f32_A(Ab, A, ks * 32, tid);
      stage_f32_B(Bb, B, ks * 32, tid);
      __syncthreads();
      h8 a[4], bf[8];
      read_fragsA(Ab, wr, lane, a);
      read_fragsB(Bb, wc, lane, bf);
      MFMA_ALL(a, bf, acc);
      __syncthreads();
    }
    const int l15 = lane & 15, hi = lane >> 4;
#pragma unroll
    for (int mi = 0; mi < 4; ++mi)
#pragma unroll
      for (int nj = 0; nj < 8; ++nj) {
        const int col = wc * 128 + nj * 16 + l15;
#pragma unroll
        for (int j = 0; j < 4; ++j) {
          const int row = wr * 64 + mi * 16 + hi * 4 + j;
          out[(size_t)row * 512 + col] = (_Float16)acc[mi][nj][j];
        }
      }
  } else if (bid < 4104) {               // key prep: 8 rows/block
    const u32* tp = (const u32*)tpos_raw;
    const bool is64 = (tp[1] == 0);
    const int row = (bid - 8) * 8 + wid;
    const int pos = (int)(is64 ? tp[2 * row] : tp[row]);
    const int d0  = lane * 8;
    const float* src = keys + (size_t)row * 512 + d0;
    const f4v a = *(const f4v*)src, b = *(const f4v*)(src + 4);
    float x[8] = {a[0], a[1], a[2], a[3], b[0], b[1], b[2], b[3]};
    if (pos != 0) {
      const float pw = (float)pos * KEY_RATE;
#pragma unroll
      for (int u = 0; u < 4; ++u) {
        const float invf = exp2f(-(float)(lane * 4 + u) * INVC);
        const float ang  = pw * invf;
        x[2*u]   += sinf(ang);
        x[2*u+1] += cosf(ang);
      }
    }
    const f4v w0 = *(const f4v*)(wvec + d0), w1 = *(const f4v*)(wvec + d0 + 4);
    float dot = 0.f;
#pragma unroll
    for (int i = 0; i < 4; ++i) dot += x[i] * w0[i] + x[4+i] * w1[i];
#pragma unroll
    for (int off = 32; off; off >>= 1) dot += __shfl_xor(dot, off);
    if (lane == 0) {
      const u32* m32 = (const u32*)mask_raw;
      const bool is32 = (m32[448] != 0);
      const bool mk = is32 ? (m32[row] != 0)
                           : (((const unsigned char*)mask_raw)[row] != 0);
      tvec[row] = mk ? -1e30f : (dot + bqbk[0]);
    }
    h8 o;
#pragma unroll
    for (int i = 0; i < 8; ++i) o[i] = (_Float16)x[i];
    *(h8*)(kp + (size_t)row * 512 + d0) = o;
  } else {                               // cvec: 8 rows/block from WoT
    const int row = (bid - 4104) * 8 + wid;
    const float* p = WoT + (size_t)row * 512 + lane * 8;
    const f4v a = *(const f4v*)p, c = *(const f4v*)(p + 4);
    const f4v b0 = *(const f4v*)(bv + lane * 8), b1 = *(const f4v*)(bv + lane * 8 + 4);
    float d = a[0]*b0[0]+a[1]*b0[1]+a[2]*b0[2]+a[3]*b0[3]
            + c[0]*b1[0]+c[1]*b1[1]+c[2]*b1[2]+c[3]*b1[3];
#pragma unroll
    for (int off = 32; off; off >>= 1) d += __shfl_xor(d, off);
    if (lane == 0) cvec[row] = SCALE * d + bo[row];
  }
}

// ---------------- mk + pv merged (counted-vmcnt pipelines) ----------------
__global__ __launch_bounds__(512, 1) void k_mkpv(
    const _Float16* __restrict__ kp, const _Float16* __restrict__ Mm,
    const float* __restrict__ values, const _Float16* __restrict__ Nt,
    _Float16* __restrict__ MKt, _Float16* __restrict__ Pt) {
  __shared__ char lds[122880];
  const int bid = blockIdx.x, tid = threadIdx.x;
  const int lane = tid & 63, wid = tid >> 6;
  const int wr = wid >> 2, wc = wid & 3;
  const int l15 = lane & 15, hi = lane >> 4;
  f4v acc[4][8] = {};
  if (bid < 256) {                       // MKt[t][c] = kp @ Mm^T
    const int tt = bid & 3, b = bid >> 2;
    const _Float16* As = kp + ((size_t)b * TKN + tt * 128) * 512;
    GLD_PIPELINE(As, Mm, acc);
    _Float16* Ob = MKt + (size_t)b * TKN * 512 + (size_t)tt * 128 * 512;
#pragma unroll
    for (int mi = 0; mi < 4; ++mi)
#pragma unroll
      for (int nj = 0; nj < 8; ++nj) {
        const int col = wc * 128 + nj * 16 + l15;
#pragma unroll
        for (int j = 0; j < 4; ++j) {
          const int row = wr * 64 + mi * 16 + hi * 4 + j;
          Ob[(size_t)row * 512 + col] = (_Float16)acc[mi][nj][j];
        }
      }
  } else {                               // Pt[e][t] = (values @ N)^T
    const int rt = (bid - 256) & 3, b = (bid - 256) >> 2;
    const float* As = values + ((size_t)b * TKN + rt * 128) * 512;
    const float* Ad = nullptr;
    REG_PIPELINE(As, Ad, Nt, acc);
    _Float16* Pb = Pt + (size_t)b * 512 * 512;
#pragma unroll
    for (int mi = 0; mi < 4; ++mi)
#pragma unroll
      for (int nj = 0; nj < 8; ++nj) {
        const int col = wc * 128 + nj * 16 + l15;
        const int t0  = rt * 128 + wr * 64 + mi * 16 + hi * 4;
        h4 o;
#pragma unroll
        for (int j = 0; j < 4; ++j) o[j] = (_Float16)acc[mi][nj][j];
        *(h4*)(Pb + (size_t)col * 512 + t0) = o;
      }
  }
}

// ---------------- scores + fused softmax (XCD-local batches) ----------------
__global__ __launch_bounds__(512, 1) void k_scores(
    const float* __restrict__ query, const float* __restrict__ PEQ,
    const _Float16* __restrict__ MKt, const float* __restrict__ tve,
    float* __restrict__ attn, _Float16* __restrict__ a16) {
  __shared__ char lds[114688];
  const int tid = threadIdx.x, lane = tid & 63, wid = tid >> 6;
  const int wr = wid >> 2, wc = wid & 3;
  const int bid = blockIdx.x;
  const int xcd = bid & 7, i = bid >> 3;
  const int qt = i & 7, b = xcd * 8 + (i >> 3);
  const float* As = query + ((size_t)b * TQ + qt * 128) * 512;
  const float* Ad = PEQ + (size_t)(qt * 128) * 512;
  const _Float16* Bs = MKt + (size_t)b * TKN * 512;
  const int l15 = lane & 15, hi = lane >> 4;
  float tv[8];
#pragma unroll
  for (int nj = 0; nj < 8; ++nj) tv[nj] = tve[b * TKN + wc * 128 + nj * 16 + l15];
  f4v acc[4][8] = {};
  REG_PIPELINE(As, Ad, Bs, acc);
  // ---- fused softmax over full 512-wide rows (red arrays reuse A0 buffer) ----
  float* red  = (float*)lds;            // [128][4]
  float* red2 = (float*)(lds + 2048);
#pragma unroll
  for (int mi = 0; mi < 4; ++mi)
#pragma unroll
    for (int nj = 0; nj < 8; ++nj) {
      const float t = tv[nj];
#pragma unroll
      for (int j = 0; j < 4; ++j) acc[mi][nj][j] += t;
    }
  float mrow[4][4];
#pragma unroll
  for (int mi = 0; mi < 4; ++mi)
#pragma unroll
    for (int j = 0; j < 4; ++j) {
      float m = acc[mi][0][j];
#pragma unroll
      for (int nj = 1; nj < 8; ++nj) m = fmaxf(m, acc[mi][nj][j]);
      m = fmaxf(m, __shfl_xor(m, 1)); m = fmaxf(m, __shfl_xor(m, 2));
      m = fmaxf(m, __shfl_xor(m, 4)); m = fmaxf(m, __shfl_xor(m, 8));
      mrow[mi][j] = m;
    }
  __syncthreads();
  if (l15 == 0) {
#pragma unroll
    for (int mi = 0; mi < 4; ++mi)
#pragma unroll
      for (int j = 0; j < 4; ++j)
        red[(wr * 64 + mi * 16 + hi * 4 + j) * 4 + wc] = mrow[mi][j];
  }
  __syncthreads();
#pragma unroll
  for (int mi = 0; mi < 4; ++mi)
#pragma unroll
    for (int j = 0; j < 4; ++j) {
      const f4v rv = *(const f4v*)(red + (wr * 64 + mi * 16 + hi * 4 + j) * 4);
      mrow[mi][j] = fmaxf(fmaxf(rv[0], rv[1]), fmaxf(rv[2], rv[3]));
    }
  float srow[4][4];
#pragma unroll
  for (int mi = 0; mi < 4; ++mi)
#pragma unroll
    for (int j = 0; j < 4; ++j) {
      float s = 0.f;
      const float m = mrow[mi][j];
#pragma unroll
      for (int nj = 0; nj < 8; ++nj) {
        const float e = expf(acc[mi][nj][j] - m);
        acc[mi][nj][j] = e; s += e;
      }
      s += __shfl_xor(s, 1); s += __shfl_xor(s, 2);
      s += __shfl_xor(s, 4); s += __shfl_xor(s, 8);
      srow[mi][j] = s;
    }
  if (l15 == 0) {
#pragma unroll
    for (int mi = 0; mi < 4; ++mi)
#pragma unroll
      for (int j = 0; j < 4; ++j)
        red2[(wr * 64 + mi * 16 + hi * 4 + j) * 4 + wc] = srow[mi][j];
  }
  __syncthreads();
  float* Ao = attn + ((size_t)b * TQ + qt * 128) * 512;
  _Float16* Ah = a16 ? a16 + ((size_t)b * TQ + qt * 128) * 512 : nullptr;
#pragma unroll
  for (int mi = 0; mi < 4; ++mi)
#pragma unroll
    for (int j = 0; j < 4; ++j) {
      const int row = wr * 64 + mi * 16 + hi * 4 + j;
      const f4v sv = *(const f4v*)(red2 + row * 4);
      const float rinv = 1.f / (sv[0] + sv[1] + sv[2] + sv[3]);
#pragma unroll
      for (int nj = 0; nj < 8; ++nj) {
        const float v = acc[mi][nj][j] * rinv;
        const int col = wc * 128 + nj * 16 + l15;
        Ao[(size_t)row * 512 + col] = v;
        if (Ah) Ah[(size_t)row * 512 + col] = (_Float16)v;
      }
    }
}

// ---------------- out = SCALE * attn @ Pt^T + cvec (XCD-local batches) ----------------
template <int A16P>
__global__ __launch_bounds__(512, 1) void k_final(
    const float* __restrict__ attn, const _Float16* __restrict__ attn16,
    const _Float16* __restrict__ Pt, const float* __restrict__ cvec,
    float* __restrict__ outp) {
  __shared__ char lds[122880];
  const int tid = threadIdx.x, lane = tid & 63, wid = tid >> 6;
  const int wr = wid >> 2, wc = wid & 3;
  const int bid = blockIdx.x;
  const int xcd = bid & 7, i = bid >> 3;
  const int qt = i & 7, b = xcd * 8 + (i >> 3);
  const _Float16* Bs = Pt + (size_t)b * 512 * 512;
  const int l15 = lane & 15, hi = lane >> 4;
  f4v acc[4][8] = {};
  if (A16P) {
    const _Float16* As = attn16 + ((size_t)b * TQ + qt * 128) * 512;
    GLD_PIPELINE(As, Bs, acc);
  } else {
    const float* As = attn + ((size_t)b * TQ + qt * 128) * 512;
    const float* Ad = nullptr;
    REG_PIPELINE(As, Ad, Bs, acc);
  }
  float cv[8];
#pragma unroll
  for (int nj = 0; nj < 8; ++nj) cv[nj] = cvec[wc * 128 + nj * 16 + l15];
  float* Ob = outp + ((size_t)b * TQ + qt * 128) * 512;
#pragma unroll
  for (int mi = 0; mi < 4; ++mi)
#pragma unroll
    for (int nj = 0; nj < 8; ++nj) {
      const int col = wc * 128 + nj * 16 + l15;
#pragma unroll
      for (int j = 0; j < 4; ++j) {
        const int row = wr * 64 + mi * 16 + hi * 4 + j;
        Ob[(size_t)row * 512 + col] = SCALE * acc[mi][nj][j] + cv[nj];
      }
    }
}

// ---------------- launcher ----------------
extern "C" void kernel_launch(void* const* d_in, const int* in_sizes, int n_in,
                              void* d_out, int out_size, void* d_ws, size_t ws_size,
                              hipStream_t stream) {
  (void)in_sizes; (void)n_in; (void)out_size;
  if (ws_size < WS_NEED) return;
  const bool big = (ws_size >= WS_BIG);

  const float* query  = (const float*)d_in[0];
  const float* keys   = (const float*)d_in[1];
  const float* values = (const float*)d_in[2];
  const void*  tpos   = d_in[3];
  const void*  fpos   = d_in[4];
  const void*  mask   = d_in[5];
  const float* Wq = (const float*)d_in[6];
  const float* bq = (const float*)d_in[7];
  const float* Wk = (const float*)d_in[8];
  const float* bk = (const float*)d_in[9];
  const float* Wv = (const float*)d_in[10];
  const float* bv = (const float*)d_in[11];
  const float* Wo = (const float*)d_in[12];
  const float* bo = (const float*)d_in[13];

  char* ws = (char*)d_ws;
  _Float16* Mm   = (_Float16*)(ws + OFF_MM);
  _Float16* Nt   = (_Float16*)(ws + OFF_NT);
  float*    WoT  = (float*)   (ws + OFF_WOT);
  float*    PEQ  = (float*)   (ws + OFF_PEQ);
  float*    wvec = (float*)   (ws + OFF_W);
  float*    cvec = (float*)   (ws + OFF_C);
  float*    bqbk = (float*)   (ws + OFF_BQBK);
  float*    tvec = (float*)   (ws + OFF_T);
  _Float16* kp   = (_Float16*)(ws + OFF_KP);
  _Float16* MKt  = (_Float16*)(ws + OFF_MKT);
  _Float16* Pt   = (_Float16*)(ws + OFF_PT);
  _Float16* a16  = big ? (_Float16*)(ws + OFF_A16) : nullptr;

  float* outp = (float*)d_out;
  float* attn = outp + (size_t)64 * TQ * 512;   // output 1 region

  k_prepA<<<2433, 256, 0, stream>>>(Wk, bq, bk, Wo, fpos, wvec, bqbk, PEQ, WoT);
  k_prepB<<<4168, 512, 0, stream>>>(Wq, Wk, WoT, Wv, keys, tpos, mask,
                                    wvec, bqbk, bv, bo, Mm, Nt, kp, tvec, cvec);
  k_mkpv <<<512, 512, 0, stream>>>(kp, Mm, values, Nt, MKt, Pt);
  k_scores<<<512, 512, 0, stream>>>(query, PEQ, MKt, tvec, attn, a16);
  if (big) k_final<1><<<512, 512, 0, stream>>>(attn, a16, Pt, cvec, outp);
  else     k_final<0><<<512, 512, 0, stream>>>(attn, a16, Pt, cvec, outp);
}